// Round 4
// baseline (123.537 us; speedup 1.0000x reference)
//
#include <hip/hip_runtime.h>

// P = dW/dF for W(F) = 8*tr(C) + 10*J^2 - 56*log(J) + 0.2*(I4^2 + I5^2) - 44
// C = F^T F, J = det F, G = diag(4, .5, .5), I4 = tr(C G), I5 = tr(cof(C) G)
// Analytic gradient:
//   P = 16 F + [20 J^2 - 56 + 0.8 I5^2] F^-T + 0.8 I4 * F G - 0.8 I5 * F^-T G cofC
// with F^-T = cof(F)/J, cofC = cof(C).
//
// R3: float2 global access + 512-sample tile = 18 KB LDS -> 8 blocks/CU
//     (100% occupancy) while doubling access width vs R0. NO swizzle (stride-9
//     f2 layout is conflict-free: banks (18t+2q) mod 32 hit all 16 even pairs
//     once per 16-lane phase), NO nt stores (R1: 4x write amplification).

typedef float f2 __attribute__((ext_vector_type(2)));

#define SAMPLES_PER_BLOCK 512
#define F2_PER_BLOCK (SAMPLES_PER_BLOCK * 9 / 2)   // 2304 f2 = 18 KB

__global__ __launch_bounds__(256, 8) void pk1_grad_kernel(
    const f2* __restrict__ Fin, f2* __restrict__ Pout, int total2)
{
    __shared__ f2 lds2[F2_PER_BLOCK];
    const int t = threadIdx.x;
    const int base2 = blockIdx.x * F2_PER_BLOCK;

    // ---- coalesced staging: global -> LDS, 8B/lane, consecutive ----
#pragma unroll
    for (int j = 0; j < 9; ++j) {
        int i = j * 256 + t;
        int g = base2 + i;
        f2 v;
        if (g < total2) v = Fin[g];
        else { v.x = 1.0f; v.y = 1.0f; }   // benign pad (discarded)
        lds2[i] = v;
    }
    __syncthreads();

    // ---- per-thread: 2 samples = 18 floats = 9 f2 at stride 9 (conflict-free) ----
    float buf[18];
#pragma unroll
    for (int q = 0; q < 9; ++q) {
        f2 v = lds2[t * 9 + q];
        buf[2 * q]     = v.x;
        buf[2 * q + 1] = v.y;
    }

#pragma unroll
    for (int s = 0; s < 2; ++s) {
        float f[9];
#pragma unroll
        for (int k = 0; k < 9; ++k) f[k] = buf[s * 9 + k];

        // cof(F): F^-T = cof(F)/J
        float c00 = f[4]*f[8] - f[5]*f[7];
        float c01 = f[5]*f[6] - f[3]*f[8];
        float c02 = f[3]*f[7] - f[4]*f[6];
        float c10 = f[2]*f[7] - f[1]*f[8];
        float c11 = f[0]*f[8] - f[2]*f[6];
        float c12 = f[1]*f[6] - f[0]*f[7];
        float c20 = f[1]*f[5] - f[2]*f[4];
        float c21 = f[2]*f[3] - f[0]*f[5];
        float c22 = f[0]*f[4] - f[1]*f[3];
        float J    = f[0]*c00 + f[1]*c01 + f[2]*c02;
        float invJ = 1.0f / J;

        // C = F^T F (symmetric)
        float C00 = f[0]*f[0] + f[3]*f[3] + f[6]*f[6];
        float C11 = f[1]*f[1] + f[4]*f[4] + f[7]*f[7];
        float C22 = f[2]*f[2] + f[5]*f[5] + f[8]*f[8];
        float C01 = f[0]*f[1] + f[3]*f[4] + f[6]*f[7];
        float C02 = f[0]*f[2] + f[3]*f[5] + f[6]*f[8];
        float C12 = f[1]*f[2] + f[4]*f[5] + f[7]*f[8];

        float I4 = 4.0f*C00 + 0.5f*(C11 + C22);

        // cof(C) (symmetric)
        float K00 = C11*C22 - C12*C12;
        float K11 = C00*C22 - C02*C02;
        float K22 = C00*C11 - C01*C01;
        float K01 = C02*C12 - C01*C22;
        float K02 = C01*C12 - C02*C11;
        float K12 = C01*C02 - C00*C12;

        float I5 = 4.0f*K00 + 0.5f*(K11 + K22);

        float J2    = J * J;
        float alpha = (20.0f*J2 - 56.0f + 0.8f*I5*I5) * invJ;  // coeff on cof(F)
        float beta  = 0.8f * I4;                                // coeff on F G
        float gamma = -0.8f * I5 * invJ;                        // coeff on cof(F) G cofC

        float cf[3][3] = {{c00,c01,c02},{c10,c11,c12},{c20,c21,c22}};
        float K[3][3]  = {{K00,K01,K02},{K01,K11,K12},{K02,K12,K22}};
        const float gv[3] = {4.0f, 0.5f, 0.5f};

#pragma unroll
        for (int i = 0; i < 3; ++i) {
            float a0 = cf[i][0] * 4.0f;
            float a1 = cf[i][1] * 0.5f;
            float a2 = cf[i][2] * 0.5f;
#pragma unroll
            for (int j = 0; j < 3; ++j) {
                float M = a0 * K[0][j] + a1 * K[1][j] + a2 * K[2][j];
                buf[s * 9 + 3 * i + j] =
                      (16.0f + beta * gv[j]) * f[3 * i + j]
                    + alpha * cf[i][j]
                    + gamma * M;
            }
        }
    }

    // results back to same LDS slots (thread-private slots; no cross-thread
    // hazard on this write, but stores below read cross-thread -> barrier)
#pragma unroll
    for (int q = 0; q < 9; ++q) {
        f2 v;
        v.x = buf[2 * q];
        v.y = buf[2 * q + 1];
        lds2[t * 9 + q] = v;
    }
    __syncthreads();

    // ---- coalesced cached stores: LDS -> global, 8B/lane ----
#pragma unroll
    for (int j = 0; j < 9; ++j) {
        int i = j * 256 + t;
        int g = base2 + i;
        if (g < total2) Pout[g] = lds2[i];
    }
}

extern "C" void kernel_launch(void* const* d_in, const int* in_sizes, int n_in,
                              void* d_out, int out_size, void* d_ws, size_t ws_size,
                              hipStream_t stream) {
    const f2* F = (const f2*)d_in[0];
    f2* P = (f2*)d_out;
    int total2 = in_sizes[0] / 2;             // 13,500,000 f2
    int blocks = (total2 + F2_PER_BLOCK - 1) / F2_PER_BLOCK;
    pk1_grad_kernel<<<blocks, 256, 0, stream>>>(F, P, total2);
}

// Round 5
// 39.745 us; speedup vs baseline: 3.1083x; 3.1083x over previous
//
#include <hip/hip_runtime.h>

// P = dW/dF for W(F) = 8*tr(C) + 10*J^2 - 56*log(J) + 0.2*(I4^2 + I5^2) - 44
// C = F^T F, J = det F, G = diag(4, .5, .5), I4 = tr(C G), I5 = tr(cof(C) G)
// Analytic gradient:
//   P = 16 F + [20 J^2 - 56 + 0.8 I5^2] F^-T + 0.8 I4 * F G - 0.8 I5 * F^-T G cofC
// with F^-T = cof(F)/J, cofC = cof(C).
//
// R4: R3 geometry (f2 global, 512-sample/18KB tile, 2 samples/thread) but
//     WITHOUT the (256,8) min-waves bound. R1/R3 post-mortem: that bound
//     forced VGPR=32 -> scratch spills -> FETCH 133MB / WRITE 281MB
//     amplification and 3x slowdown. Natural allocation (~56-64 VGPR, no
//     spill) still allows 8 waves/SIMD + 8 blocks/CU via 18KB LDS.

typedef float f2 __attribute__((ext_vector_type(2)));

#define SAMPLES_PER_BLOCK 512
#define F2_PER_BLOCK (SAMPLES_PER_BLOCK * 9 / 2)   // 2304 f2 = 18 KB

__global__ __launch_bounds__(256) void pk1_grad_kernel(
    const f2* __restrict__ Fin, f2* __restrict__ Pout, int total2)
{
    __shared__ f2 lds2[F2_PER_BLOCK];
    const int t = threadIdx.x;
    const int base2 = blockIdx.x * F2_PER_BLOCK;

    // ---- coalesced staging: global -> LDS, 8B/lane, consecutive ----
#pragma unroll
    for (int j = 0; j < 9; ++j) {
        int i = j * 256 + t;
        int g = base2 + i;
        f2 v;
        if (g < total2) v = Fin[g];
        else { v.x = 1.0f; v.y = 1.0f; }   // benign pad (results discarded)
        lds2[i] = v;
    }
    __syncthreads();

    // ---- per-thread: 2 samples = 18 floats = 9 f2 at stride 9 (2-way alias, free) ----
    float buf[18];
#pragma unroll
    for (int q = 0; q < 9; ++q) {
        f2 v = lds2[t * 9 + q];
        buf[2 * q]     = v.x;
        buf[2 * q + 1] = v.y;
    }

#pragma unroll
    for (int s = 0; s < 2; ++s) {
        float f[9];
#pragma unroll
        for (int k = 0; k < 9; ++k) f[k] = buf[s * 9 + k];

        // cof(F): F^-T = cof(F)/J
        float c00 = f[4]*f[8] - f[5]*f[7];
        float c01 = f[5]*f[6] - f[3]*f[8];
        float c02 = f[3]*f[7] - f[4]*f[6];
        float c10 = f[2]*f[7] - f[1]*f[8];
        float c11 = f[0]*f[8] - f[2]*f[6];
        float c12 = f[1]*f[6] - f[0]*f[7];
        float c20 = f[1]*f[5] - f[2]*f[4];
        float c21 = f[2]*f[3] - f[0]*f[5];
        float c22 = f[0]*f[4] - f[1]*f[3];
        float J    = f[0]*c00 + f[1]*c01 + f[2]*c02;
        float invJ = 1.0f / J;

        // C = F^T F (symmetric)
        float C00 = f[0]*f[0] + f[3]*f[3] + f[6]*f[6];
        float C11 = f[1]*f[1] + f[4]*f[4] + f[7]*f[7];
        float C22 = f[2]*f[2] + f[5]*f[5] + f[8]*f[8];
        float C01 = f[0]*f[1] + f[3]*f[4] + f[6]*f[7];
        float C02 = f[0]*f[2] + f[3]*f[5] + f[6]*f[8];
        float C12 = f[1]*f[2] + f[4]*f[5] + f[7]*f[8];

        float I4 = 4.0f*C00 + 0.5f*(C11 + C22);

        // cof(C) (symmetric)
        float K00 = C11*C22 - C12*C12;
        float K11 = C00*C22 - C02*C02;
        float K22 = C00*C11 - C01*C01;
        float K01 = C02*C12 - C01*C22;
        float K02 = C01*C12 - C02*C11;
        float K12 = C01*C02 - C00*C12;

        float I5 = 4.0f*K00 + 0.5f*(K11 + K22);

        float J2    = J * J;
        float alpha = (20.0f*J2 - 56.0f + 0.8f*I5*I5) * invJ;  // coeff on cof(F)
        float beta  = 0.8f * I4;                                // coeff on F G
        float gamma = -0.8f * I5 * invJ;                        // coeff on cof(F) G cofC

        float cf[3][3] = {{c00,c01,c02},{c10,c11,c12},{c20,c21,c22}};
        float K[3][3]  = {{K00,K01,K02},{K01,K11,K12},{K02,K12,K22}};
        const float gv[3] = {4.0f, 0.5f, 0.5f};

#pragma unroll
        for (int i = 0; i < 3; ++i) {
            float a0 = cf[i][0] * 4.0f;
            float a1 = cf[i][1] * 0.5f;
            float a2 = cf[i][2] * 0.5f;
#pragma unroll
            for (int j = 0; j < 3; ++j) {
                float M = a0 * K[0][j] + a1 * K[1][j] + a2 * K[2][j];
                buf[s * 9 + 3 * i + j] =
                      (16.0f + beta * gv[j]) * f[3 * i + j]
                    + alpha * cf[i][j]
                    + gamma * M;
            }
        }
    }

    // ---- results back to LDS (thread-private slots), then barrier ----
#pragma unroll
    for (int q = 0; q < 9; ++q) {
        f2 v;
        v.x = buf[2 * q];
        v.y = buf[2 * q + 1];
        lds2[t * 9 + q] = v;
    }
    __syncthreads();

    // ---- coalesced cached stores: LDS -> global, 8B/lane ----
#pragma unroll
    for (int j = 0; j < 9; ++j) {
        int i = j * 256 + t;
        int g = base2 + i;
        if (g < total2) Pout[g] = lds2[i];
    }
}

extern "C" void kernel_launch(void* const* d_in, const int* in_sizes, int n_in,
                              void* d_out, int out_size, void* d_ws, size_t ws_size,
                              hipStream_t stream) {
    const f2* F = (const f2*)d_in[0];
    f2* P = (f2*)d_out;
    int total2 = in_sizes[0] / 2;             // 13,500,000 f2
    int blocks = (total2 + F2_PER_BLOCK - 1) / F2_PER_BLOCK;
    pk1_grad_kernel<<<blocks, 256, 0, stream>>>(F, P, total2);
}